// Round 10
// baseline (117.242 us; speedup 1.0000x reference)
//
#include <hip/hip_runtime.h>
#include <hip/hip_bf16.h>

#define HW    3136
#define C_IN  256
#define G_    16
#define GC_   16
#define IMGH  56
#define IMGW  56
#define EPSV  1e-5f

#define PROWS 62          // xpad rows (h-3 .. h+58)
#define XROW  64          // xpad row stride in bf16 (128 B)
#define SXCH4 648         // s_x per-channel stride in shorts (10*64 + 8 pad; 324 words ≡ 4 mod 32)
#define SKR   2744        // s_kern per-output-row plane: 49 taps * 56 floats
#define SWSTR 264         // s_w row stride in shorts (256 + 8 pad)

typedef __bf16 bf16x8 __attribute__((ext_vector_type(8)));
typedef float  f32x4  __attribute__((ext_vector_type(4)));
typedef float  f32x2  __attribute__((ext_vector_type(2)));

static __device__ __forceinline__ unsigned short f2bf(float f) {
    union { float f; unsigned u; } v; v.f = f;
    unsigned r = (v.u + 0x7FFFu + ((v.u >> 16) & 1u)) >> 16;   // RNE
    return (unsigned short)r;
}
static __device__ __forceinline__ float bfu_lo(unsigned u) {
    union { unsigned u; float f; } v; v.u = u << 16; return v.f;
}
static __device__ __forceinline__ float bfu_hi(unsigned u) {
    union { unsigned u; float f; } v; v.u = u & 0xffff0000u; return v.f;
}

// ---------------------------------------------------------------------------
// k_front: one launch, three independent roles.  (unchanged from R9)
//  blocks 0..495   : xpad bf16 [1024][62][64], zero-padded by 3
//  blocks 496..544 : Wsbf = bf16(W_span)
//  blocks 545..740 : reduce-GEMM -> xrT[pix][64] bf16 (196 blocks)
// ---------------------------------------------------------------------------
__global__ __launch_bounds__(256) void k_front(
    const float* __restrict__ x, const float* __restrict__ Wr,
    const float* __restrict__ Wspan, const float* __restrict__ br,
    const float* __restrict__ gamma, const float* __restrict__ beta,
    const float* __restrict__ mean, const float* __restrict__ var,
    unsigned short* __restrict__ xpad, unsigned short* __restrict__ Wsbf,
    unsigned short* __restrict__ xrT)
{
    __shared__ __align__(16) unsigned short s_w[64 * SWSTR];   // 33792 B
    int blk = blockIdx.x, t = threadIdx.x;

    if (blk < 496) {
        // ---- xpad staging ----
        int F0 = blk * 1024 + t;
#pragma unroll
        for (int it = 0; it < 4; ++it) {
            int F   = F0 + it * 256;              // < 507904 = 1024*496
            int bc  = F / 496;
            int rem = F - bc * 496;
            int row = rem >> 3, oct = rem & 7;
            int hr  = row - 3;
            const float* xs = x + (size_t)bc * HW + hr * IMGW;
            union { unsigned short s[8]; uint4 v; } pk;
#pragma unroll
            for (int j = 0; j < 8; ++j) {
                int wc = oct * 8 + j - 3;
                float vv = (hr >= 0 && hr < IMGH && wc >= 0 && wc < IMGW) ? xs[wc] : 0.f;
                pk.s[j] = f2bf(vv);
            }
            *(uint4*)(xpad + ((size_t)bc * PROWS + row) * XROW + oct * 8) = pk.v;
        }
    } else if (blk < 545) {
        // ---- W_span -> bf16 ----
        int i4 = ((blk - 496) * 256 + t) * 4;     // < 50176 exactly at 49 blocks
#pragma unroll
        for (int j = 0; j < 4; ++j) Wsbf[i4 + j] = f2bf(Wspan[i4 + j]);
    } else {
        // ---- reduce GEMM ----
        int bi = blk - 545;                        // 0..195
        int wv = t >> 6, lane = t & 63;
        int ln = lane & 15, quad = lane >> 4;
        int p  = bi * 64 + wv * 16 + ln;
        int b  = bi / 49;
        int l  = p - b * HW;
        const float* xb = x + (size_t)b * C_IN * HW + l;

        // preload all 64 x values (strided, all in flight)
        float xv[64];
#pragma unroll
        for (int ks = 0; ks < 8; ++ks)
#pragma unroll
            for (int j = 0; j < 8; ++j)
                xv[ks * 8 + j] = xb[(size_t)(ks * 32 + quad * 8 + j) * HW];

        // stage W_reduce -> LDS bf16
        {
            int row = t >> 2, col0 = (t & 3) * 64;
            const float* wsrc = Wr + t * 64;
#pragma unroll
            for (int k = 0; k < 8; ++k) {
                union { unsigned short s[8]; uint4 v; } pk;
#pragma unroll
                for (int j = 0; j < 8; ++j) pk.s[j] = f2bf(wsrc[k * 8 + j]);
                *(uint4*)&s_w[row * SWSTR + col0 + k * 8] = pk.v;
            }
        }
        __syncthreads();

        f32x4 acc[4];
#pragma unroll
        for (int mt = 0; mt < 4; ++mt) acc[mt] = (f32x4){0.f, 0.f, 0.f, 0.f};

#pragma unroll
        for (int ks = 0; ks < 8; ++ks) {
            union { unsigned short s[8]; bf16x8 v; } bfx;
#pragma unroll
            for (int j = 0; j < 8; ++j) bfx.s[j] = f2bf(xv[ks * 8 + j]);
            int c0 = ks * 32 + quad * 8;
#pragma unroll
            for (int mt = 0; mt < 4; ++mt) {
                bf16x8 af = *(const bf16x8*)&s_w[(mt * 16 + ln) * SWSTR + c0];
                acc[mt] = __builtin_amdgcn_mfma_f32_16x16x32_bf16(af, bfx.v, acc[mt], 0, 0, 0);
            }
        }
#pragma unroll
        for (int mt = 0; mt < 4; ++mt) {
            union { unsigned short s[4]; uint2 v; } pk;
#pragma unroll
            for (int r = 0; r < 4; ++r) {
                int o = mt * 16 + quad * 4 + r;
                float s  = gamma[o] * rsqrtf(var[o] + EPSV);
                float vv = (acc[mt][r] + br[o] - mean[o]) * s + beta[o];
                pk.s[r] = f2bf(fmaxf(vv, 0.f));
            }
            *(uint2*)(xrT + (size_t)p * 64 + mt * 16 + quad * 4) = pk.v;
        }
    }
}

// ---------------------------------------------------------------------------
// k_invol: block = (b, g, 4-row quad). 512 thr, 896 blocks. LDS 63.1 KB.
//  stage: 16ch x 10 rows x 128B via global_load_lds (1KB full-wave + 256B
//         16-lane tail per channel)
//  Phase A: kern[4][49][56] = Wspan_g @ xr + bias; 14 MFMAs/wave (4m x 14n
//           tiles over 224 contiguous pixels), fp32 to LDS.
//  Phase B: 224 thr = 8 cp x 4 rows x 7 w-octs; 8w x 2c per thread
//           (c = cp + 8*ci); kern float4 b128 broadcast, x b128; f32x2 FMA.
// ---------------------------------------------------------------------------
__global__ __launch_bounds__(512, 4) void k_invol(
    const unsigned short* __restrict__ xpad, const unsigned short* __restrict__ xrT,
    const unsigned short* __restrict__ Wsbf, const float* __restrict__ bspan,
    float* __restrict__ out)
{
    __shared__ __align__(16) unsigned short s_x[GC_ * SXCH4];  // 20736 B
    __shared__ __align__(16) float s_kern[4 * SKR];            // 43904 B

    int t = threadIdx.x;
    int bid = blockIdx.x;
    int xcd = bid & 7, jj = bid >> 3;          // XCD-stripe swizzle
    int g = jj & 15, rq7 = jj >> 4;            // rq7 in [0,7)
    int idx = xcd * 7 + rq7;                   // [0,56) = 4 b x 14 row-quads
    int b = idx / 14, rq = idx - b * 14;
    int h0 = rq * 4;

    int wv = t >> 6, lane = t & 63;

    // ---- async stage x: wave wv loads channels 2wv, 2wv+1 (1.25 KB each) ----
#pragma unroll
    for (int i = 0; i < 2; ++i) {
        int c = wv * 2 + i;
        const unsigned short* gsrc = xpad
            + ((size_t)(b * C_IN + g * GC_ + c) * PROWS + h0) * XROW;
        __builtin_amdgcn_global_load_lds(
            (const __attribute__((address_space(1))) void*)(gsrc + lane * 8),
            (__attribute__((address_space(3))) void*)&s_x[c * SXCH4],
            16, 0, 0);
        if (lane < 16)
            __builtin_amdgcn_global_load_lds(
                (const __attribute__((address_space(1))) void*)(gsrc + 512 + lane * 8),
                (__attribute__((address_space(3))) void*)&s_x[c * SXCH4 + 512],
                16, 0, 0);
    }

    // ---- Phase A: kern = Wspan_g @ xr + bias (MFMA, fp32 store) ----
    {
        int ln = lane & 15, quad = lane >> 4;
        int mt = wv & 3, nh = wv >> 2;          // 4 m-tiles x 2 n-halves (7 tiles each)
        int m0 = mt * 16;
        int ko_a = m0 + ln; if (ko_a > 48) ko_a = 48;
        const unsigned short* wrow = Wsbf + (size_t)(g * 49 + ko_a) * 64;
        int pixbase = b * HW + h0 * IMGW;      // 224 contiguous pixels

        f32x4 acc[7];
#pragma unroll
        for (int nt = 0; nt < 7; ++nt) acc[nt] = (f32x4){0.f, 0.f, 0.f, 0.f};

#pragma unroll
        for (int ks = 0; ks < 2; ++ks) {
            int c0 = ks * 32 + quad * 8;
            bf16x8 af = *(const bf16x8*)(wrow + c0);
#pragma unroll
            for (int nt = 0; nt < 7; ++nt) {
                int pp = (nh * 7 + nt) * 16 + ln;   // < 224
                bf16x8 bb = *(const bf16x8*)(xrT + (size_t)(pixbase + pp) * 64 + c0);
                acc[nt] = __builtin_amdgcn_mfma_f32_16x16x32_bf16(af, bb, acc[nt], 0, 0, 0);
            }
        }
#pragma unroll
        for (int r = 0; r < 4; ++r) {
            int ko = m0 + quad * 4 + r;
            float bias = bspan[g * 49 + (ko < 49 ? ko : 48)];
#pragma unroll
            for (int nt = 0; nt < 7; ++nt) {
                if (ko < 49) {
                    int pp = (nh * 7 + nt) * 16 + ln;
                    int prow = pp / 56, pw = pp - prow * 56;
                    s_kern[prow * SKR + ko * 56 + pw] = acc[nt][r] + bias;
                }
            }
        }
    }
    __syncthreads();

    // ---- Phase B: 224 thr, each 8 w x 2 c x 1 row (c = cp + 8*ci) ----
    if (t < 224) {
        int wp  = t % 7;                        // 0..6
        int row = (t / 7) & 3;                  // 0..3
        int cp  = t / 28;                       // 0..7
        int w0  = wp * 8;

        const float* sk = s_kern + row * SKR + w0;
        f32x2 acc[2][4];
#pragma unroll
        for (int ci = 0; ci < 2; ++ci)
#pragma unroll
            for (int j = 0; j < 4; ++j) acc[ci][j] = (f32x2){0.f, 0.f};

#pragma unroll
        for (int r = 0; r < 7; ++r) {
            float xf[2][16];
#pragma unroll
            for (int ci = 0; ci < 2; ++ci) {
                const unsigned short* sx =
                    s_x + (cp + 8 * ci) * SXCH4 + (row + r) * XROW + w0;
                uint4 xu0 = *(const uint4*)sx;
                uint4 xu1 = *(const uint4*)(sx + 8);
                const unsigned* xw0 = (const unsigned*)&xu0;
                const unsigned* xw1 = (const unsigned*)&xu1;
#pragma unroll
                for (int k = 0; k < 4; ++k) {
                    xf[ci][2 * k]         = bfu_lo(xw0[k]);
                    xf[ci][2 * k + 1]     = bfu_hi(xw0[k]);
                    xf[ci][8 + 2 * k]     = bfu_lo(xw1[k]);
                    xf[ci][8 + 2 * k + 1] = bfu_hi(xw1[k]);
                }
            }
#pragma unroll
            for (int dw = 0; dw < 7; ++dw) {
                float4 ka = *(const float4*)(sk + (r * 7 + dw) * 56);
                float4 kb = *(const float4*)(sk + (r * 7 + dw) * 56 + 4);
                f32x2 k01 = (f32x2){ka.x, ka.y};
                f32x2 k23 = (f32x2){ka.z, ka.w};
                f32x2 k45 = (f32x2){kb.x, kb.y};
                f32x2 k67 = (f32x2){kb.z, kb.w};
#pragma unroll
                for (int ci = 0; ci < 2; ++ci) {
                    acc[ci][0] += k01 * (f32x2){xf[ci][dw],     xf[ci][dw + 1]};
                    acc[ci][1] += k23 * (f32x2){xf[ci][dw + 2], xf[ci][dw + 3]};
                    acc[ci][2] += k45 * (f32x2){xf[ci][dw + 4], xf[ci][dw + 5]};
                    acc[ci][3] += k67 * (f32x2){xf[ci][dw + 6], xf[ci][dw + 7]};
                }
            }
        }
#pragma unroll
        for (int ci = 0; ci < 2; ++ci) {
            float* ob = out + (size_t)(b * C_IN + g * GC_ + cp + 8 * ci) * HW
                            + (h0 + row) * IMGW + w0;
            *(float4*)ob       = make_float4(acc[ci][0][0], acc[ci][0][1],
                                             acc[ci][1][0], acc[ci][1][1]);
            *(float4*)(ob + 4) = make_float4(acc[ci][2][0], acc[ci][2][1],
                                             acc[ci][3][0], acc[ci][3][1]);
        }
    }
}

// ---------------------------------------------------------------------------
extern "C" void kernel_launch(void* const* d_in, const int* in_sizes, int n_in,
                              void* d_out, int out_size, void* d_ws, size_t ws_size,
                              hipStream_t stream)
{
    const float* x   = (const float*)d_in[0];
    const float* Wr  = (const float*)d_in[1];
    const float* br  = (const float*)d_in[2];
    const float* gm  = (const float*)d_in[3];
    const float* bt  = (const float*)d_in[4];
    const float* mn  = (const float*)d_in[5];
    const float* vr  = (const float*)d_in[6];
    const float* Ws  = (const float*)d_in[7];
    const float* bs  = (const float*)d_in[8];
    float* out = (float*)d_out;

    char* ws = (char*)d_ws;
    unsigned short* xrT  = (unsigned short*)ws;                 // 1,605,632 B
    unsigned short* xpad = (unsigned short*)(ws + 1605632);     // 8,126,464 B
    unsigned short* Wsbf = (unsigned short*)(ws + 9732096);     //   100,352 B

    k_front <<<dim3(741), 256, 0, stream>>>(x, Wr, Ws, br, gm, bt, mn, vr,
                                            xpad, Wsbf, xrT);
    k_invol <<<dim3(896), 512, 0, stream>>>(xpad, xrT, Wsbf, bs, out);
}

// Round 11
// 113.081 us; speedup vs baseline: 1.0368x; 1.0368x over previous
//
#include <hip/hip_runtime.h>
#include <hip/hip_bf16.h>

#define HW    3136
#define C_IN  256
#define G_    16
#define GC_   16
#define IMGH  56
#define IMGW  56
#define EPSV  1e-5f

#define PROWS 62          // xpad rows (h-3 .. h+58)
#define XROW  64          // xpad row stride in bf16 (128 B)
#define SXCH  536         // s_x per-channel stride in shorts (268 words ≡ 12 mod 32 banks)
#define SKROW 2940        // s_kern per-output-row plane: 49 * 60 floats
#define SWSTR 264         // s_w row stride in shorts (256 + 8 pad)

typedef __bf16 bf16x8 __attribute__((ext_vector_type(8)));
typedef float  f32x4  __attribute__((ext_vector_type(4)));
typedef float  f32x2  __attribute__((ext_vector_type(2)));

static __device__ __forceinline__ unsigned short f2bf(float f) {
    union { float f; unsigned u; } v; v.f = f;
    unsigned r = (v.u + 0x7FFFu + ((v.u >> 16) & 1u)) >> 16;   // RNE
    return (unsigned short)r;
}
static __device__ __forceinline__ float bfu_lo(unsigned u) {
    union { unsigned u; float f; } v; v.u = u << 16; return v.f;
}
static __device__ __forceinline__ float bfu_hi(unsigned u) {
    union { unsigned u; float f; } v; v.u = u & 0xffff0000u; return v.f;
}

// ---------------------------------------------------------------------------
// k_front: one launch, three independent roles.
//  blocks 0..495   : xpad bf16 [1024][62][64], zero-padded by 3
//  blocks 496..544 : Wsbf = bf16(W_span)
//  blocks 545..740 : reduce-GEMM -> xrT[pix][64] bf16 (196 blocks)
// ---------------------------------------------------------------------------
__global__ __launch_bounds__(256) void k_front(
    const float* __restrict__ x, const float* __restrict__ Wr,
    const float* __restrict__ Wspan, const float* __restrict__ br,
    const float* __restrict__ gamma, const float* __restrict__ beta,
    const float* __restrict__ mean, const float* __restrict__ var,
    unsigned short* __restrict__ xpad, unsigned short* __restrict__ Wsbf,
    unsigned short* __restrict__ xrT)
{
    __shared__ __align__(16) unsigned short s_w[64 * SWSTR];   // 33792 B
    int blk = blockIdx.x, t = threadIdx.x;

    if (blk < 496) {
        // ---- xpad staging ----
        int F0 = blk * 1024 + t;
#pragma unroll
        for (int it = 0; it < 4; ++it) {
            int F   = F0 + it * 256;              // < 507904 = 1024*496
            int bc  = F / 496;
            int rem = F - bc * 496;
            int row = rem >> 3, oct = rem & 7;
            int hr  = row - 3;
            const float* xs = x + (size_t)bc * HW + hr * IMGW;
            union { unsigned short s[8]; uint4 v; } pk;
#pragma unroll
            for (int j = 0; j < 8; ++j) {
                int wc = oct * 8 + j - 3;
                float vv = (hr >= 0 && hr < IMGH && wc >= 0 && wc < IMGW) ? xs[wc] : 0.f;
                pk.s[j] = f2bf(vv);
            }
            *(uint4*)(xpad + ((size_t)bc * PROWS + row) * XROW + oct * 8) = pk.v;
        }
    } else if (blk < 545) {
        // ---- W_span -> bf16 ----
        int i4 = ((blk - 496) * 256 + t) * 4;     // < 50176 exactly at 49 blocks
#pragma unroll
        for (int j = 0; j < 4; ++j) Wsbf[i4 + j] = f2bf(Wspan[i4 + j]);
    } else {
        // ---- reduce GEMM ----
        int bi = blk - 545;                        // 0..195
        int wv = t >> 6, lane = t & 63;
        int ln = lane & 15, quad = lane >> 4;
        int p  = bi * 64 + wv * 16 + ln;
        int b  = bi / 49;
        int l  = p - b * HW;
        const float* xb = x + (size_t)b * C_IN * HW + l;

        // preload all 64 x values (strided, all in flight)
        float xv[64];
#pragma unroll
        for (int ks = 0; ks < 8; ++ks)
#pragma unroll
            for (int j = 0; j < 8; ++j)
                xv[ks * 8 + j] = xb[(size_t)(ks * 32 + quad * 8 + j) * HW];

        // stage W_reduce -> LDS bf16
        {
            int row = t >> 2, col0 = (t & 3) * 64;
            const float* wsrc = Wr + t * 64;
#pragma unroll
            for (int k = 0; k < 8; ++k) {
                union { unsigned short s[8]; uint4 v; } pk;
#pragma unroll
                for (int j = 0; j < 8; ++j) pk.s[j] = f2bf(wsrc[k * 8 + j]);
                *(uint4*)&s_w[row * SWSTR + col0 + k * 8] = pk.v;
            }
        }
        __syncthreads();

        f32x4 acc[4];
#pragma unroll
        for (int mt = 0; mt < 4; ++mt) acc[mt] = (f32x4){0.f, 0.f, 0.f, 0.f};

#pragma unroll
        for (int ks = 0; ks < 8; ++ks) {
            union { unsigned short s[8]; bf16x8 v; } bfx;
#pragma unroll
            for (int j = 0; j < 8; ++j) bfx.s[j] = f2bf(xv[ks * 8 + j]);
            int c0 = ks * 32 + quad * 8;
#pragma unroll
            for (int mt = 0; mt < 4; ++mt) {
                bf16x8 af = *(const bf16x8*)&s_w[(mt * 16 + ln) * SWSTR + c0];
                acc[mt] = __builtin_amdgcn_mfma_f32_16x16x32_bf16(af, bfx.v, acc[mt], 0, 0, 0);
            }
        }
#pragma unroll
        for (int mt = 0; mt < 4; ++mt) {
            union { unsigned short s[4]; uint2 v; } pk;
#pragma unroll
            for (int r = 0; r < 4; ++r) {
                int o = mt * 16 + quad * 4 + r;
                float s  = gamma[o] * rsqrtf(var[o] + EPSV);
                float vv = (acc[mt][r] + br[o] - mean[o]) * s + beta[o];
                pk.s[r] = f2bf(fmaxf(vv, 0.f));
            }
            *(uint2*)(xrT + (size_t)p * 64 + mt * 16 + quad * 4) = pk.v;
        }
    }
}

// ---------------------------------------------------------------------------
// k_invol: block = (b, g, row-pair). 512 thr. LDS 40.7 KB -> 3 blocks/CU.
//  stage: 16 x 1KB global_load_lds (xpad bf16 -> s_x, SXCH=536 anti-conflict)
//  Phase A: kern[2][49][56] = Wspan_g @ xr + bias (MFMA, fp32 to LDS).
//    112 px = exactly 7 n-tiles of 16 -> no padded 8th tile, no clamp.
//  Phase B: 112 thr = 8 cp x 2 rows x 7 w-octs; 8w x 2c per thread
//           (c = cp + 8*ci); kern float4 b128, x 2 b128 per row; f32x2 FMA.
// ---------------------------------------------------------------------------
__global__ __launch_bounds__(512, 4) void k_invol(
    const unsigned short* __restrict__ xpad, const unsigned short* __restrict__ xrT,
    const unsigned short* __restrict__ Wsbf, const float* __restrict__ bspan,
    float* __restrict__ out)
{
    __shared__ __align__(16) unsigned short s_x[GC_ * SXCH];   // 17152 B
    __shared__ __align__(16) float s_kern[2 * SKROW];          // 23520 B

    int t = threadIdx.x;
    int bid = blockIdx.x;
    int xcd = bid & 7, jj = bid >> 3;          // XCD-stripe swizzle
    int g = jj & 15, rpb = jj >> 4;            // rpb in [0,14)
    int idx = xcd * 14 + rpb;                  // [0,112) = 4 b x 28 row-pairs
    int b = idx / 28, rp = idx - b * 28;
    int h0 = rp * 2;

    int wv = t >> 6, lane = t & 63;

    // ---- async stage x: wave wv loads channels 2wv, 2wv+1 (1 KB each) ----
#pragma unroll
    for (int i = 0; i < 2; ++i) {
        int c = wv * 2 + i;
        const unsigned short* gsrc = xpad
            + ((size_t)(b * C_IN + g * GC_ + c) * PROWS + h0) * XROW + lane * 8;
        __builtin_amdgcn_global_load_lds(
            (const __attribute__((address_space(1))) void*)gsrc,
            (__attribute__((address_space(3))) void*)&s_x[c * SXCH],
            16, 0, 0);
    }

    // ---- Phase A: kern = Wspan_g @ xr + bias (MFMA, fp32 store) ----
    {
        int ln = lane & 15, quad = lane >> 4;
        int mt = wv & 3, nh = wv >> 2;          // 4 m-tiles x 2 n-groups (4+3)
        int m0 = mt * 16;
        int ko_a = m0 + ln; if (ko_a > 48) ko_a = 48;
        const unsigned short* wrow = Wsbf + (size_t)(g * 49 + ko_a) * 64;
        int pixbase = b * HW + h0 * IMGW;      // 112 contiguous pixels

        f32x4 acc[4];
#pragma unroll
        for (int nt = 0; nt < 4; ++nt) acc[nt] = (f32x4){0.f, 0.f, 0.f, 0.f};

#pragma unroll
        for (int ks = 0; ks < 2; ++ks) {
            int c0 = ks * 32 + quad * 8;
            bf16x8 af = *(const bf16x8*)(wrow + c0);
#pragma unroll
            for (int nt = 0; nt < 4; ++nt) {
                int tile = nh * 4 + nt;
                if (tile > 6) continue;        // wave-uniform skip (nh==1, nt==3)
                int pp = tile * 16 + ln;       // always < 112
                bf16x8 bb = *(const bf16x8*)(xrT + (size_t)(pixbase + pp) * 64 + c0);
                acc[nt] = __builtin_amdgcn_mfma_f32_16x16x32_bf16(af, bb, acc[nt], 0, 0, 0);
            }
        }
#pragma unroll
        for (int r = 0; r < 4; ++r) {
            int ko = m0 + quad * 4 + r;
            float bias = bspan[g * 49 + (ko < 49 ? ko : 48)];
#pragma unroll
            for (int nt = 0; nt < 4; ++nt) {
                int tile = nh * 4 + nt;
                if (tile > 6) continue;
                int pp = tile * 16 + ln;
                if (ko < 49) {
                    int prow = pp / 56, pw = pp - prow * 56;
                    s_kern[prow * SKROW + ko * 60 + pw] = acc[nt][r] + bias;
                }
            }
        }
    }
    __syncthreads();

    // ---- Phase B: 112 thr, each 8 w x 2 c (c = cp + 8*ci) ----
    if (t < 112) {
        int wp  = t % 7;                        // 0..6
        int row = (t / 7) & 1;                  // 0..1
        int cp  = t / 14;                       // 0..7
        int w0  = wp * 8;

        const float* sk = s_kern + row * SKROW + w0;
        f32x2 acc[2][4];
#pragma unroll
        for (int ci = 0; ci < 2; ++ci)
#pragma unroll
            for (int j = 0; j < 4; ++j) acc[ci][j] = (f32x2){0.f, 0.f};

#pragma unroll
        for (int r = 0; r < 7; ++r) {
            float xf[2][16];
#pragma unroll
            for (int ci = 0; ci < 2; ++ci) {
                const unsigned short* sx =
                    s_x + (cp + 8 * ci) * SXCH + (row + r) * XROW + w0;
                uint4 xu0 = *(const uint4*)sx;
                uint4 xu1 = *(const uint4*)(sx + 8);
                const unsigned* xw0 = (const unsigned*)&xu0;
                const unsigned* xw1 = (const unsigned*)&xu1;
#pragma unroll
                for (int k = 0; k < 4; ++k) {
                    xf[ci][2 * k]         = bfu_lo(xw0[k]);
                    xf[ci][2 * k + 1]     = bfu_hi(xw0[k]);
                    xf[ci][8 + 2 * k]     = bfu_lo(xw1[k]);
                    xf[ci][8 + 2 * k + 1] = bfu_hi(xw1[k]);
                }
            }
#pragma unroll
            for (int dw = 0; dw < 7; ++dw) {
                float4 ka = *(const float4*)(sk + (r * 7 + dw) * 60);
                float4 kb = *(const float4*)(sk + (r * 7 + dw) * 60 + 4);
                f32x2 k01 = (f32x2){ka.x, ka.y};
                f32x2 k23 = (f32x2){ka.z, ka.w};
                f32x2 k45 = (f32x2){kb.x, kb.y};
                f32x2 k67 = (f32x2){kb.z, kb.w};
#pragma unroll
                for (int ci = 0; ci < 2; ++ci) {
                    acc[ci][0] += k01 * (f32x2){xf[ci][dw],     xf[ci][dw + 1]};
                    acc[ci][1] += k23 * (f32x2){xf[ci][dw + 2], xf[ci][dw + 3]};
                    acc[ci][2] += k45 * (f32x2){xf[ci][dw + 4], xf[ci][dw + 5]};
                    acc[ci][3] += k67 * (f32x2){xf[ci][dw + 6], xf[ci][dw + 7]};
                }
            }
        }
#pragma unroll
        for (int ci = 0; ci < 2; ++ci) {
            float* ob = out + (size_t)(b * C_IN + g * GC_ + cp + 8 * ci) * HW
                            + (h0 + row) * IMGW + w0;
            *(float4*)ob       = make_float4(acc[ci][0][0], acc[ci][0][1],
                                             acc[ci][1][0], acc[ci][1][1]);
            *(float4*)(ob + 4) = make_float4(acc[ci][2][0], acc[ci][2][1],
                                             acc[ci][3][0], acc[ci][3][1]);
        }
    }
}

// ---------------------------------------------------------------------------
extern "C" void kernel_launch(void* const* d_in, const int* in_sizes, int n_in,
                              void* d_out, int out_size, void* d_ws, size_t ws_size,
                              hipStream_t stream)
{
    const float* x   = (const float*)d_in[0];
    const float* Wr  = (const float*)d_in[1];
    const float* br  = (const float*)d_in[2];
    const float* gm  = (const float*)d_in[3];
    const float* bt  = (const float*)d_in[4];
    const float* mn  = (const float*)d_in[5];
    const float* vr  = (const float*)d_in[6];
    const float* Ws  = (const float*)d_in[7];
    const float* bs  = (const float*)d_in[8];
    float* out = (float*)d_out;

    char* ws = (char*)d_ws;
    unsigned short* xrT  = (unsigned short*)ws;                 // 1,605,632 B
    unsigned short* xpad = (unsigned short*)(ws + 1605632);     // 8,126,464 B
    unsigned short* Wsbf = (unsigned short*)(ws + 9732096);     //   100,352 B

    k_front <<<dim3(741),  256, 0, stream>>>(x, Wr, Ws, br, gm, bt, mn, vr,
                                             xpad, Wsbf, xrT);
    k_invol <<<dim3(1792), 512, 0, stream>>>(xpad, xrT, Wsbf, bs, out);
}